// Round 5
// baseline (248.293 us; speedup 1.0000x reference)
//
#include <hip/hip_runtime.h>

// AssociativeMemoryStep — chunked linear attention, fully MFMA.
// Round 5: split-K=8 on xb GEMM (occupancy 1->4 blk/CU), double-buffered LDS
// staging in mgemm (one barrier/iter, loads overlap MFMA).
// B=4 T=4096 V=1024 F=128 C=256, chunk Tc=64 (G=64).

#define Bb 4
#define Tt 4096
#define Vv 1024
#define Ff 128
#define Cc 256
#define TC 64
#define Gg (Tt / TC)
#define QLD 768  // q|k|v row stride (elements)

typedef __attribute__((ext_vector_type(8))) short short8;
typedef __attribute__((ext_vector_type(4))) float f32x4;

__device__ __forceinline__ float dsigmoid(const float* p) {
    return 1.0f / (1.0f + expf(-p[0]));
}
__device__ __forceinline__ ushort f2bf(float f) {
    unsigned u = __float_as_uint(f);
    u = (u + 0x7FFFu + ((u >> 16) & 1u)) >> 16;
    return (ushort)u;
}
__device__ __forceinline__ float bf2f(ushort u) {
    return __uint_as_float(((unsigned)u) << 16);
}

// ---------------------------------------------------------------- weight prep
__global__ __launch_bounds__(256) void prep_weights(
    const float* __restrict__ basis, const float* __restrict__ qc,
    const float* __restrict__ kc, const float* __restrict__ vc,
    const float* __restrict__ oc,
    ushort* __restrict__ basisTb,   // [128][1024] = basis^T bf16
    ushort* __restrict__ qkvc,      // [768][128]  = concat(qc,kc,vc) bf16
    ushort* __restrict__ ocb)       // [256][128]  = oc bf16
{
    int i = blockIdx.x * 256 + threadIdx.x;
    if (i < Ff * Vv) {
        int f = i >> 10, v = i & 1023;
        basisTb[i] = f2bf(basis[v * Ff + f]);
    }
    if (i < 768 * Ff) {
        int ch = i >> 7, f = i & 127;
        const float* src = ch < 256 ? qc : (ch < 512 ? kc : vc);
        qkvc[i] = f2bf(src[(ch & 255) * Ff + f]);
    }
    if (i < Cc * Ff) ocb[i] = f2bf(oc[i]);
}

// ---------------------------------------------------------------- MFMA GEMM
// C[M,N] = A[M,K] @ Bt[N,K]^T.  BM=BN=128, BK=32, 4 waves (2x2), 64x64/wave.
// Double-buffered LDS: one barrier/iter, next tile's loads overlap MFMA.
// AMODE: 0 = A bf16, 1 = A fp32.
// OMODE: 0 bf16 out; 1 fp32*alpha; 3 bf16 slab (split-K partials).
template<int AMODE, int OMODE>
__global__ __launch_bounds__(256) void mgemm(
    const void* __restrict__ Ap, const ushort* __restrict__ Bt,
    void* __restrict__ Cp, int N_total, int K_total, int ldA, int Ksplit,
    const float* __restrict__ alpha_ptr)
{
    __shared__ ushort Asm[2][128][40];
    __shared__ ushort Bsm[2][128][40];
    const int tid = threadIdx.x;
    const int row0 = blockIdx.x * 128;
    const int col0 = blockIdx.y * 128;
    const int kb = blockIdx.z * Ksplit;
    const int kend = kb + Ksplit;

    const int trow = tid >> 1;
    const int thalf = (tid & 1) * 16;

    const int l = tid & 63, w = tid >> 6;
    const int wr = (w >> 1) * 64, wc = (w & 1) * 64;
    const int lrow = l & 15, lk = l >> 4;

    f32x4 acc[4][4];
#pragma unroll
    for (int mi = 0; mi < 4; ++mi)
#pragma unroll
        for (int ni = 0; ni < 4; ++ni) {
            f32x4 z = {0.f, 0.f, 0.f, 0.f};
            acc[mi][ni] = z;
        }

    // staging registers
    float4 fa0, fa1, fa2, fa3;   // AMODE==1
    int4 ia0, ia1;               // AMODE==0
    int4 ib0, ib1;

    // ---- load tile(kb) into regs
#define LOAD_TILE(K0)                                                              \
    do {                                                                           \
        if (AMODE == 1) {                                                          \
            const float* ap = (const float*)Ap + (size_t)(row0 + trow) * ldA + (K0) + thalf; \
            fa0 = ((const float4*)ap)[0]; fa1 = ((const float4*)ap)[1];            \
            fa2 = ((const float4*)ap)[2]; fa3 = ((const float4*)ap)[3];            \
        } else {                                                                   \
            const ushort* ap = (const ushort*)Ap + (size_t)(row0 + trow) * ldA + (K0) + thalf; \
            ia0 = ((const int4*)ap)[0]; ia1 = ((const int4*)ap)[1];                \
        }                                                                          \
        const ushort* bp = Bt + (size_t)(col0 + trow) * K_total + (K0) + thalf;    \
        ib0 = ((const int4*)bp)[0]; ib1 = ((const int4*)bp)[1];                    \
    } while (0)

#define STORE_TILE(BUF)                                                            \
    do {                                                                           \
        if (AMODE == 1) {                                                          \
            union { ushort us[16]; int4 i4[2]; } t;                                \
            t.us[0] = f2bf(fa0.x); t.us[1] = f2bf(fa0.y); t.us[2] = f2bf(fa0.z); t.us[3] = f2bf(fa0.w); \
            t.us[4] = f2bf(fa1.x); t.us[5] = f2bf(fa1.y); t.us[6] = f2bf(fa1.z); t.us[7] = f2bf(fa1.w); \
            t.us[8] = f2bf(fa2.x); t.us[9] = f2bf(fa2.y); t.us[10] = f2bf(fa2.z); t.us[11] = f2bf(fa2.w); \
            t.us[12] = f2bf(fa3.x); t.us[13] = f2bf(fa3.y); t.us[14] = f2bf(fa3.z); t.us[15] = f2bf(fa3.w); \
            *(int4*)&Asm[BUF][trow][thalf] = t.i4[0];                              \
            *(int4*)&Asm[BUF][trow][thalf + 8] = t.i4[1];                          \
        } else {                                                                   \
            *(int4*)&Asm[BUF][trow][thalf] = ia0;                                  \
            *(int4*)&Asm[BUF][trow][thalf + 8] = ia1;                              \
        }                                                                          \
        *(int4*)&Bsm[BUF][trow][thalf] = ib0;                                      \
        *(int4*)&Bsm[BUF][trow][thalf + 8] = ib1;                                  \
    } while (0)

    LOAD_TILE(kb);
    STORE_TILE(0);
    int cur = 0;

    for (int k0 = kb; k0 < kend; k0 += 32) {
        __syncthreads();                      // LDS[cur] ready
        const bool more = (k0 + 32 < kend);
        if (more) LOAD_TILE(k0 + 32);         // loads in flight over MFMA
        short8 af[4], bf[4];
#pragma unroll
        for (int mi = 0; mi < 4; ++mi)
            af[mi] = *(const short8*)&Asm[cur][wr + mi * 16 + lrow][lk * 8];
#pragma unroll
        for (int ni = 0; ni < 4; ++ni)
            bf[ni] = *(const short8*)&Bsm[cur][wc + ni * 16 + lrow][lk * 8];
#pragma unroll
        for (int mi = 0; mi < 4; ++mi)
#pragma unroll
            for (int ni = 0; ni < 4; ++ni)
                acc[mi][ni] = __builtin_amdgcn_mfma_f32_16x16x32_bf16(
                    af[mi], bf[ni], acc[mi][ni], 0, 0, 0);
        if (more) STORE_TILE(cur ^ 1);
        cur ^= 1;
    }
#undef LOAD_TILE
#undef STORE_TILE

    const float alpha = (OMODE == 1) ? alpha_ptr[0] : 1.0f;
    size_t slab = (OMODE == 3) ? (size_t)blockIdx.z * (size_t)gridDim.x * 128 * N_total : 0;
#pragma unroll
    for (int mi = 0; mi < 4; ++mi) {
#pragma unroll
        for (int ni = 0; ni < 4; ++ni) {
#pragma unroll
            for (int r = 0; r < 4; ++r) {
                int row = row0 + wr + mi * 16 + lk * 4 + r;
                int col = col0 + wc + ni * 16 + lrow;
                size_t idx = slab + (size_t)row * N_total + col;
                if (OMODE == 1) ((float*)Cp)[idx] = acc[mi][ni][r] * alpha;
                else ((ushort*)Cp)[idx] = f2bf(acc[mi][ni][r]);
            }
        }
    }
}

// ---------------------------------------------------------------- split-K reduce (8 slabs, bf16)
__global__ __launch_bounds__(256) void reduce_xb(
    const ushort* __restrict__ p, ushort* __restrict__ xb)
{
    const size_t SLAB = (size_t)Bb * Tt * Ff;
    size_t i = ((size_t)blockIdx.x * 256 + threadIdx.x) * 8;
    float s[8] = {0.f, 0.f, 0.f, 0.f, 0.f, 0.f, 0.f, 0.f};
#pragma unroll
    for (int z = 0; z < 8; ++z) {
        union { int4 v; ushort us[8]; } t;
        t.v = *(const int4*)(p + z * SLAB + i);
#pragma unroll
        for (int j = 0; j < 8; ++j) s[j] += bf2f(t.us[j]);
    }
    union { int4 v; ushort us[8]; } o;
#pragma unroll
    for (int j = 0; j < 8; ++j) o.us[j] = f2bf(s[j]);
    *(int4*)(xb + i) = o.v;
}

// ---------------------------------------------------------------- K/V transpose
// Kts[b][c][t] = d^{t&63} * K[b][t][c] ; Vt[b][c][t] = V[b][t][c]  (bf16)
__global__ __launch_bounds__(256) void transpose_kv(
    const ushort* __restrict__ qkv, ushort* __restrict__ Kts,
    ushort* __restrict__ Vt, const float* __restrict__ dlogit)
{
    __shared__ ushort tile[64][72];
    __shared__ float dp[64];
    const int tid = threadIdx.x;
    const int t0 = blockIdx.x * 64, c0 = blockIdx.y * 64;
    const int b = blockIdx.z >> 1, mat = blockIdx.z & 1;  // 0=K, 1=V
    const float d = dsigmoid(dlogit);
    if (tid < 64) dp[tid] = powf(d, (float)tid);
    const int coff = 256 + mat * 256 + c0;
#pragma unroll
    for (int j = 0; j < 2; ++j) {
        int row = (tid >> 3) + j * 32;
        int seg = (tid & 7) * 8;
        *(int4*)&tile[row][seg] =
            *(const int4*)(qkv + ((size_t)(b * Tt + t0 + row)) * QLD + coff + seg);
    }
    __syncthreads();
    const int cl = tid & 63, tb = (tid >> 6) * 16;
    ushort* outp = (mat ? Vt : Kts) + ((size_t)(b * Cc + c0 + cl)) * Tt + t0 + tb;
#pragma unroll
    for (int h = 0; h < 2; ++h) {
        union { ushort us[8]; int4 v; } o;
#pragma unroll
        for (int jj = 0; jj < 8; ++jj) {
            int tl = tb + h * 8 + jj;
            ushort val = tile[tl][cl];
            if (mat == 0) val = f2bf(bf2f(val) * dp[tl]);
            o.us[jj] = val;
        }
        *(int4*)(outp + h * 8) = o.v;
    }
}

// ---------------------------------------------------------------- chunk outer products (MFMA)
// LT[b][g][c][c'] = sum_s Vt[c][s] * Kts[c'][s]  (= L[c'][c]), bf16 out.
__global__ __launch_bounds__(256) void chunk_lt(
    const ushort* __restrict__ Kts, const ushort* __restrict__ Vt,
    ushort* __restrict__ LT)
{
    const int tid = threadIdx.x;
    const int g = blockIdx.y, b = blockIdx.z;
    const int c0 = (blockIdx.x & 1) * 128, cp0 = (blockIdx.x >> 1) * 128;
    const int w = tid >> 6, l = tid & 63;
    const int wc = (w >> 1) * 64, wcp = (w & 1) * 64;
    const int lrow = l & 15, lk = l >> 4;

    f32x4 acc[4][4];
#pragma unroll
    for (int mi = 0; mi < 4; ++mi)
#pragma unroll
        for (int ni = 0; ni < 4; ++ni) {
            f32x4 z = {0.f, 0.f, 0.f, 0.f};
            acc[mi][ni] = z;
        }
#pragma unroll
    for (int ks = 0; ks < 2; ++ks) {
        short8 af[4], bf[4];
#pragma unroll
        for (int mi = 0; mi < 4; ++mi)
            af[mi] = *(const short8*)(Vt +
                ((size_t)(b * Cc + c0 + wc + mi * 16 + lrow)) * Tt + g * TC + ks * 32 + lk * 8);
#pragma unroll
        for (int ni = 0; ni < 4; ++ni)
            bf[ni] = *(const short8*)(Kts +
                ((size_t)(b * Cc + cp0 + wcp + ni * 16 + lrow)) * Tt + g * TC + ks * 32 + lk * 8);
#pragma unroll
        for (int mi = 0; mi < 4; ++mi)
#pragma unroll
            for (int ni = 0; ni < 4; ++ni)
                acc[mi][ni] = __builtin_amdgcn_mfma_f32_16x16x32_bf16(
                    af[mi], bf[ni], acc[mi][ni], 0, 0, 0);
    }
    ushort* lb = LT + (((size_t)(b * Gg + g)) << 16);
#pragma unroll
    for (int mi = 0; mi < 4; ++mi)
#pragma unroll
        for (int ni = 0; ni < 4; ++ni)
#pragma unroll
            for (int r = 0; r < 4; ++r)
                lb[(size_t)(c0 + wc + mi * 16 + lk * 4 + r) * Cc + cp0 + wcp + ni * 16 + lrow]
                    = f2bf(acc[mi][ni][r]);
}

// ---------------------------------------------------------------- reverse scan
// SbT[b][g] = LT[b][g+1] + d^Tc * state ; SbT[b][G-1] = 0.  (bf16 in/out)
__global__ __launch_bounds__(64) void scan_kernel(
    const ushort* __restrict__ LT, ushort* __restrict__ SbT,
    const float* __restrict__ dlogit)
{
    const int e = blockIdx.x * 64 + threadIdx.x;
    const int b = blockIdx.y;
    const float d = dsigmoid(dlogit);
    const float dTc = powf(d, (float)TC);
    const size_t CC = (size_t)Cc * Cc;
    const size_t base = (size_t)b * Gg * CC + e;
    SbT[base + (size_t)(Gg - 1) * CC] = 0;
    float cur = 0.f;
    ushort nxt = LT[base + (size_t)(Gg - 1) * CC];  // LT[g+1] for g=G-2
    for (int g = Gg - 2; g >= 0; --g) {
        float L = bf2f(nxt);
        if (g > 0) nxt = LT[base + (size_t)g * CC];  // prefetch
        cur = L + dTc * cur;
        SbT[base + (size_t)g * CC] = f2bf(cur);
    }
}

// ---------------------------------------------------------------- attention (MFMA)
// One block per (g,b), 4 waves. retr[64,256] =
//   P @ V  (P[t][s] = (s>t) d^{s-t-1} q_t.k_s)  +  d^{63-t} * (Q @ SbT rows)
__global__ __launch_bounds__(256) void attn_mfma(
    const ushort* __restrict__ qkv, const ushort* __restrict__ SbT,
    const ushort* __restrict__ Vt, ushort* __restrict__ retrb,
    const float* __restrict__ dlogit)
{
    __shared__ ushort Qsm[64][264];
    __shared__ ushort Ksm[64][264];
    __shared__ ushort Psm[64][72];
    __shared__ float dpow[64];
    const int tid = threadIdx.x;
    const int g = blockIdx.x, b = blockIdx.y;
    const float d = dsigmoid(dlogit);
    if (tid < 64) dpow[tid] = powf(d, (float)tid);

    const ushort* qb = qkv + ((size_t)(b * Tt + g * TC)) * QLD;
#pragma unroll
    for (int j = 0; j < 8; ++j) {
        int seg = tid + 256 * j;
        int row = seg >> 5, sc = (seg & 31) * 8;
        *(int4*)&Qsm[row][sc] = *(const int4*)(qb + (size_t)row * QLD + sc);
        *(int4*)&Ksm[row][sc] = *(const int4*)(qb + (size_t)row * QLD + 256 + sc);
    }
    __syncthreads();

    const int w = tid >> 6, l = tid & 63;
    const int lrow = l & 15, lk = l >> 4;

    // ---- QK^T: wave w computes P cols [w*16, w*16+16)
    f32x4 acc1[4];
#pragma unroll
    for (int mi = 0; mi < 4; ++mi) { f32x4 z = {0.f,0.f,0.f,0.f}; acc1[mi] = z; }
#pragma unroll
    for (int ks = 0; ks < 8; ++ks) {
        short8 bf = *(const short8*)&Ksm[w * 16 + lrow][ks * 32 + lk * 8];
#pragma unroll
        for (int mi = 0; mi < 4; ++mi) {
            short8 af = *(const short8*)&Qsm[mi * 16 + lrow][ks * 32 + lk * 8];
            acc1[mi] = __builtin_amdgcn_mfma_f32_16x16x32_bf16(af, bf, acc1[mi], 0, 0, 0);
        }
    }
#pragma unroll
    for (int mi = 0; mi < 4; ++mi)
#pragma unroll
        for (int r = 0; r < 4; ++r) {
            int t = mi * 16 + lk * 4 + r, s = w * 16 + lrow;
            float p = (s > t) ? acc1[mi][r] * dpow[s - t - 1] : 0.f;
            Psm[t][s] = f2bf(p);
        }
    __syncthreads();

    // ---- retr accumulator: wave w covers cols [w*64, w*64+64)
    f32x4 acc[4][4];
#pragma unroll
    for (int mi = 0; mi < 4; ++mi)
#pragma unroll
        for (int ni = 0; ni < 4; ++ni) {
            f32x4 z = {0.f, 0.f, 0.f, 0.f};
            acc[mi][ni] = z;
        }

    // part B: Q @ S (SbT rows are S columns), K=256
    const ushort* Sg = SbT + (((size_t)(b * Gg + g)) << 16);
#pragma unroll
    for (int ks = 0; ks < 8; ++ks) {
        short8 af[4], bf[4];
#pragma unroll
        for (int mi = 0; mi < 4; ++mi)
            af[mi] = *(const short8*)&Qsm[mi * 16 + lrow][ks * 32 + lk * 8];
#pragma unroll
        for (int ni = 0; ni < 4; ++ni)
            bf[ni] = *(const short8*)(Sg +
                (size_t)(w * 64 + ni * 16 + lrow) * Cc + ks * 32 + lk * 8);
#pragma unroll
        for (int mi = 0; mi < 4; ++mi)
#pragma unroll
            for (int ni = 0; ni < 4; ++ni)
                acc[mi][ni] = __builtin_amdgcn_mfma_f32_16x16x32_bf16(
                    af[mi], bf[ni], acc[mi][ni], 0, 0, 0);
    }
    // scale inter-chunk term by d^{63 - t}
#pragma unroll
    for (int mi = 0; mi < 4; ++mi) {
#pragma unroll
        for (int r = 0; r < 4; ++r) {
            float wq = dpow[63 - (mi * 16 + lk * 4 + r)];
#pragma unroll
            for (int ni = 0; ni < 4; ++ni) acc[mi][ni][r] *= wq;
        }
    }
    // part A: P @ Vt, K=64
#pragma unroll
    for (int ks = 0; ks < 2; ++ks) {
        short8 af[4], bf[4];
#pragma unroll
        for (int mi = 0; mi < 4; ++mi)
            af[mi] = *(const short8*)&Psm[mi * 16 + lrow][ks * 32 + lk * 8];
#pragma unroll
        for (int ni = 0; ni < 4; ++ni)
            bf[ni] = *(const short8*)(Vt +
                ((size_t)(b * Cc + w * 64 + ni * 16 + lrow)) * Tt + g * TC + ks * 32 + lk * 8);
#pragma unroll
        for (int mi = 0; mi < 4; ++mi)
#pragma unroll
            for (int ni = 0; ni < 4; ++ni)
                acc[mi][ni] = __builtin_amdgcn_mfma_f32_16x16x32_bf16(
                    af[mi], bf[ni], acc[mi][ni], 0, 0, 0);
    }

    ushort* rb = retrb + ((size_t)(b * Tt + g * TC)) * Cc;
#pragma unroll
    for (int mi = 0; mi < 4; ++mi)
#pragma unroll
        for (int ni = 0; ni < 4; ++ni)
#pragma unroll
            for (int r = 0; r < 4; ++r)
                rb[(size_t)(mi * 16 + lk * 4 + r) * Cc + w * 64 + ni * 16 + lrow]
                    = f2bf(acc[mi][ni][r]);
}

// ---------------------------------------------------------------- launch
extern "C" void kernel_launch(void* const* d_in, const int* in_sizes, int n_in,
                              void* d_out, int out_size, void* d_ws, size_t ws_size,
                              hipStream_t stream) {
    const float* x      = (const float*)d_in[0];
    const float* basis  = (const float*)d_in[1];
    const float* qc     = (const float*)d_in[2];
    const float* kc     = (const float*)d_in[3];
    const float* vc     = (const float*)d_in[4];
    const float* oc     = (const float*)d_in[5];
    const float* dlogit = (const float*)d_in[6];
    const float* oscale = (const float*)d_in[7];
    float* out = (float*)d_out;

    char* w = (char*)d_ws;
    ushort* basisTb = (ushort*)w;  w += (size_t)Ff * Vv * 2;
    ushort* qkvc    = (ushort*)w;  w += (size_t)768 * Ff * 2;
    ushort* ocb     = (ushort*)w;  w += (size_t)Cc * Ff * 2;
    ushort* ow      = (ushort*)w;  w += (size_t)Vv * Cc * 2;
    ushort* xb      = (ushort*)w;  w += (size_t)Bb * Tt * Ff * 2;
    ushort* qkv     = (ushort*)w;  w += (size_t)Bb * Tt * QLD * 2;
    ushort* Kts     = (ushort*)w;  w += (size_t)Bb * Cc * Tt * 2;
    ushort* Vt      = (ushort*)w;  w += (size_t)Bb * Cc * Tt * 2;
    ushort* LT      = (ushort*)w;  w += (size_t)Bb * Gg * Cc * Cc * 2;   // also xb partials (disjoint lifetime)
    ushort* SbT     = (ushort*)w;  w += (size_t)Bb * Gg * Cc * Cc * 2;
    ushort* retrb   = (ushort*)w;  w += (size_t)Bb * Tt * Cc * 2;
    ushort* xbp     = LT;          // 8 slabs x 4.2MB = 33.5MB, dead before chunk_lt

    prep_weights<<<512, 256, 0, stream>>>(basis, qc, kc, vc, oc, basisTb, qkvc, ocb);
    // o_w = basis @ oc^T : [1024,256], K=128
    mgemm<1, 0><<<dim3(8, 2), 256, 0, stream>>>(basis, ocb, ow, Cc, Ff, Ff, Ff, nullptr);
    // xb partials = x @ basisT^T : split-K 8x128 -> bf16 slabs
    mgemm<1, 3><<<dim3(128, 1, 8), 256, 0, stream>>>(x, basisTb, xbp, Ff, Vv, Vv, 128, nullptr);
    reduce_xb<<<1024, 256, 0, stream>>>(xbp, xb);
    // qkv = xb @ qkvc^T : [16384,768], K=128
    mgemm<0, 0><<<dim3(128, 6), 256, 0, stream>>>(xb, qkvc, qkv, QLD, Ff, Ff, Ff, nullptr);
    // K/V transpose (+decay pre-scale on K)
    transpose_kv<<<dim3(Tt / 64, Cc / 64, Bb * 2), 256, 0, stream>>>(qkv, Kts, Vt, dlogit);
    // per-chunk outer products (MFMA) -> LT bf16
    chunk_lt<<<dim3(4, Gg, Bb), 256, 0, stream>>>(Kts, Vt, LT);
    // reverse scan -> SbT bf16
    scan_kernel<<<dim3(Cc * Cc / 64, Bb), 64, 0, stream>>>(LT, SbT, dlogit);
    // attention core (MFMA) -> retr bf16
    attn_mfma<<<dim3(Gg, Bb), 256, 0, stream>>>(qkv, SbT, Vt, retrb, dlogit);
    // out = retr @ o_w^T * out_scale : [16384,1024], K=256
    mgemm<0, 1><<<dim3(128, 8), 256, 0, stream>>>(retrb, ow, out, Vv, Cc, Cc, Cc, oscale);
}